// Round 1
// baseline (363.607 us; speedup 1.0000x reference)
//
#include <hip/hip_runtime.h>

#define N_NODES 100000
#define D_FEAT 128
#define N_CLASSES 32

// Kernel 1: y = x @ W^T (into ws), out = y + b (into d_out).
// thread -> (node, class): 32 consecutive lanes share a node.
__global__ __launch_bounds__(256) void gin_project(
    const float* __restrict__ x, const float* __restrict__ W,
    const float* __restrict__ b, float* __restrict__ y,
    float* __restrict__ out) {
    __shared__ float Wt[D_FEAT * N_CLASSES];  // Wt[d*32 + c] = W[c*128 + d]
    __shared__ float bs[N_CLASSES];

    int tid = threadIdx.x;
    for (int i = tid; i < D_FEAT * N_CLASSES; i += 256) {
        int c = i >> 7;       // W is [C][D] row-major
        int d = i & 127;
        Wt[d * N_CLASSES + c] = W[i];
    }
    if (tid < N_CLASSES) bs[tid] = b[tid];
    __syncthreads();

    int gid = blockIdx.x * 256 + tid;
    int n = gid >> 5;
    int c = gid & 31;
    if (n >= N_NODES) return;

    const float4* xr = (const float4*)(x + (size_t)n * D_FEAT);
    float acc = 0.f;
#pragma unroll 8
    for (int d4 = 0; d4 < D_FEAT / 4; ++d4) {
        float4 xv = xr[d4];  // same addr across the 32-lane group -> broadcast
        int base = d4 * 4 * N_CLASSES + c;
        acc += xv.x * Wt[base];
        acc += xv.y * Wt[base + N_CLASSES];
        acc += xv.z * Wt[base + 2 * N_CLASSES];
        acc += xv.w * Wt[base + 3 * N_CLASSES];
    }
    size_t o = (size_t)n * N_CLASSES + c;
    y[o] = acc;
    out[o] = acc + bs[c];
}

// Kernel 2: for each edge (s -> d): out[d][c] += y[s][c]
// thread -> (edge, class); 32-lane group per edge.
__global__ __launch_bounds__(256) void gin_scatter(
    const int* __restrict__ src, const int* __restrict__ dst,
    const float* __restrict__ y, float* __restrict__ out, int n_edges) {
    long long gid = (long long)blockIdx.x * 256 + threadIdx.x;
    int e = (int)(gid >> 5);
    int c = (int)(gid & 31);
    if (e >= n_edges) return;
    int s = src[e];  // broadcast within the group
    int d = dst[e];
    float v = y[(size_t)s * N_CLASSES + c];  // coalesced 128B per group
    atomicAdd(&out[(size_t)d * N_CLASSES + c], v);
}

extern "C" void kernel_launch(void* const* d_in, const int* in_sizes, int n_in,
                              void* d_out, int out_size, void* d_ws, size_t ws_size,
                              hipStream_t stream) {
    const float* x = (const float*)d_in[0];
    const int* edge_index = (const int*)d_in[1];  // [2, E] row-major int32
    const float* W = (const float*)d_in[2];
    const float* b = (const float*)d_in[3];
    float* out = (float*)d_out;

    int n_edges = in_sizes[1] / 2;
    const int* src = edge_index;
    const int* dst = edge_index + n_edges;

    float* y = (float*)d_ws;  // N_NODES * N_CLASSES floats = 12.8 MB

    // Kernel 1: projection. 100000*32 threads.
    int threads1 = N_NODES * N_CLASSES;
    int grid1 = (threads1 + 255) / 256;
    gin_project<<<grid1, 256, 0, stream>>>(x, W, b, y, out);

    // Kernel 2: scatter-add. n_edges*32 threads.
    long long threads2 = (long long)n_edges * N_CLASSES;
    int grid2 = (int)((threads2 + 255) / 256);
    gin_scatter<<<grid2, 256, 0, stream>>>(src, dst, y, out, n_edges);
}